// Round 1
// baseline (827.343 us; speedup 1.0000x reference)
//
#include <hip/hip_runtime.h>

#define NEG_SLOPE 0.01f

// ---------------- CSR build ----------------

__global__ void count_kernel(const int* __restrict__ dst, int* __restrict__ cnt, int E) {
    int e = blockIdx.x * blockDim.x + threadIdx.x;
    if (e < E) atomicAdd(&cnt[dst[e]], 1);
}

__global__ void dis_kernel(const int* __restrict__ cnt, float* __restrict__ dis, int N) {
    int i = blockIdx.x * blockDim.x + threadIdx.x;
    if (i < N) dis[i] = rsqrtf((float)cnt[i] + 1.0f);  // +1 = self loop
}

// single-block exclusive scan of cnt[N] -> rowptr[N+1]
__global__ __launch_bounds__(1024) void scan_kernel(const int* __restrict__ cnt,
                                                    int* __restrict__ rowptr, int N) {
    __shared__ int lds[1024];
    int t = threadIdx.x;
    int CPT = (N + 1023) >> 10;
    int begin = t * CPT;
    int end = begin + CPT; if (end > N) end = N;
    int s = 0;
    for (int i = begin; i < end; i++) s += cnt[i];
    lds[t] = s;
    __syncthreads();
    for (int off = 1; off < 1024; off <<= 1) {
        int v = (t >= off) ? lds[t - off] : 0;
        __syncthreads();
        lds[t] += v;
        __syncthreads();
    }
    int run = lds[t] - s;  // exclusive prefix
    for (int i = begin; i < end; i++) { rowptr[i] = run; run += cnt[i]; }
    if (t == 1023) rowptr[N] = run;
}

__global__ void fill_kernel(const int* __restrict__ src, const int* __restrict__ dst,
                            const int* __restrict__ rowptr, int* __restrict__ fill,
                            int* __restrict__ col, int E) {
    int e = blockIdx.x * blockDim.x + threadIdx.x;
    if (e < E) {
        int d = dst[e];
        int pos = rowptr[d] + atomicAdd(&fill[d], 1);
        col[pos] = src[e];
    }
}

__global__ void pick_kernel(const int* __restrict__ batch, int* __restrict__ picked, int N) {
    int i = blockIdx.x * blockDim.x + threadIdx.x;
    if (i >= N) return;
    if (i == 0 || batch[i] != batch[i - 1]) picked[batch[i]] = i;
}

// ---------------- aggregation: out[i] = dis_i * (sum_{s in N(i)} dis_s*h[s] + dis_i*h[i]) ----------------

template <int VEC> __device__ inline void loadv(const float* p, float* r);
template <> __device__ inline void loadv<2>(const float* p, float* r) {
    float2 v = *(const float2*)p; r[0] = v.x; r[1] = v.y;
}
template <> __device__ inline void loadv<4>(const float* p, float* r) {
    float4 v = *(const float4*)p; r[0] = v.x; r[1] = v.y; r[2] = v.z; r[3] = v.w;
}
template <int VEC> __device__ inline void storev(float* p, const float* r);
template <> __device__ inline void storev<2>(float* p, const float* r) {
    *(float2*)p = make_float2(r[0], r[1]);
}
template <> __device__ inline void storev<4>(float* p, const float* r) {
    *(float4*)p = make_float4(r[0], r[1], r[2], r[3]);
}

// one 64-lane wave per node; F = VEC*64 features
template <int VEC>
__global__ __launch_bounds__(256) void agg_kernel(const float* __restrict__ h,
                                                  const float* __restrict__ dis,
                                                  const int* __restrict__ rowptr,
                                                  const int* __restrict__ col,
                                                  float* __restrict__ out, int N) {
    const int F = VEC * 64;
    int wid = blockIdx.x * 4 + (threadIdx.x >> 6);
    if (wid >= N) return;
    int lane = threadIdx.x & 63;
    float di = dis[wid];

    float acc[VEC], tmp[VEC];
    loadv<VEC>(h + (size_t)wid * F + lane * VEC, tmp);
#pragma unroll
    for (int v = 0; v < VEC; v++) acc[v] = di * tmp[v];  // self-loop term

    int e0 = rowptr[wid], e1 = rowptr[wid + 1];
    for (int e = e0; e < e1; e++) {
        int s = col[e];
        float w = dis[s];
        loadv<VEC>(h + (size_t)s * F + lane * VEC, tmp);
#pragma unroll
        for (int v = 0; v < VEC; v++) acc[v] += w * tmp[v];
    }
#pragma unroll
    for (int v = 0; v < VEC; v++) acc[v] *= di;
    storev<VEC>(out + (size_t)wid * F + lane * VEC, acc);
}

// ---------------- f32 GEMM: C[M x 256] = A[M x K] @ W[K x 256] (+bias, optional leaky) ----------------

template <int K, bool RELU>
__global__ __launch_bounds__(256) void gemm_f32(const float* __restrict__ A,
                                                const float* __restrict__ W,
                                                const float* __restrict__ bias,
                                                float* __restrict__ C, int M) {
    constexpr int NC = 256;
    constexpr int BM = 128, BN = 128, BK = 16;
    __shared__ float As[BK][BM];  // transposed A tile
    __shared__ float Bs[BK][BN];

    int row0 = blockIdx.x * BM;
    int col0 = blockIdx.y * BN;
    int t = threadIdx.x;
    int tx = t & 15, ty = t >> 4;  // 16x16 threads, 8x8 outputs each

    float acc[8][8] = {};

    for (int k0 = 0; k0 < K; k0 += BK) {
        // A tile: BM x BK, 512 float4 units
#pragma unroll
        for (int u = t; u < BM * BK / 4; u += 256) {
            int r = u >> 2;
            int c4 = (u & 3) * 4;
            int gr = row0 + r;
            float4 v = (gr < M) ? *(const float4*)(A + (size_t)gr * K + k0 + c4)
                                : make_float4(0.f, 0.f, 0.f, 0.f);
            As[c4 + 0][r] = v.x; As[c4 + 1][r] = v.y;
            As[c4 + 2][r] = v.z; As[c4 + 3][r] = v.w;
        }
        // W tile: BK x BN, 512 float4 units
#pragma unroll
        for (int u = t; u < BK * BN / 4; u += 256) {
            int kr = u >> 5;
            int c4 = (u & 31) * 4;
            *(float4*)&Bs[kr][c4] = *(const float4*)(W + (size_t)(k0 + kr) * NC + col0 + c4);
        }
        __syncthreads();
#pragma unroll
        for (int k = 0; k < BK; k++) {
            float a[8], b[8];
            *(float4*)&a[0] = *(float4*)&As[k][ty * 8];
            *(float4*)&a[4] = *(float4*)&As[k][ty * 8 + 4];
            *(float4*)&b[0] = *(float4*)&Bs[k][tx * 8];
            *(float4*)&b[4] = *(float4*)&Bs[k][tx * 8 + 4];
#pragma unroll
            for (int i = 0; i < 8; i++)
#pragma unroll
                for (int j = 0; j < 8; j++) acc[i][j] += a[i] * b[j];
        }
        __syncthreads();
    }

#pragma unroll
    for (int i = 0; i < 8; i++) {
        int gr = row0 + ty * 8 + i;
        if (gr >= M) continue;
#pragma unroll
        for (int j = 0; j < 8; j += 4) {
            int gc = col0 + tx * 8 + j;
            float4 v;
            v.x = acc[i][j + 0] + bias[gc + 0];
            v.y = acc[i][j + 1] + bias[gc + 1];
            v.z = acc[i][j + 2] + bias[gc + 2];
            v.w = acc[i][j + 3] + bias[gc + 3];
            if (RELU) {
                v.x = v.x > 0.f ? v.x : NEG_SLOPE * v.x;
                v.y = v.y > 0.f ? v.y : NEG_SLOPE * v.y;
                v.z = v.z > 0.f ? v.z : NEG_SLOPE * v.z;
                v.w = v.w > 0.f ? v.w : NEG_SLOPE * v.w;
            }
            *(float4*)(C + (size_t)gr * NC + gc) = v;
        }
    }
}

// ---------------- small GEMM: C[M x 16] = A[M x 256] @ W[256 x 16] (no bias) ----------------

__global__ __launch_bounds__(256) void gemm16(const float* __restrict__ A,
                                              const float* __restrict__ W,
                                              float* __restrict__ C, int M) {
    __shared__ float Ws[256][16];
    __shared__ float Hs[16][256];
    int t = threadIdx.x;
#pragma unroll
    for (int u = t; u < 256 * 16 / 4; u += 256) {
        int k = u >> 2;
        int c = (u & 3) * 4;
        *(float4*)&Ws[k][c] = *(const float4*)(W + k * 16 + c);
    }
    int row0 = blockIdx.x * 16;
#pragma unroll
    for (int u = t; u < 16 * 256 / 4; u += 256) {
        int r = u >> 6;
        int c = (u & 63) * 4;
        int gr = row0 + r;
        float4 v = (gr < M) ? *(const float4*)(A + (size_t)gr * 256 + c)
                            : make_float4(0.f, 0.f, 0.f, 0.f);
        *(float4*)&Hs[r][c] = v;
    }
    __syncthreads();
    int colc = t & 15, r = t >> 4;
    float acc = 0.f;
#pragma unroll 8
    for (int k = 0; k < 256; k++) acc += Hs[r][k] * Ws[k][colc];
    int gr = row0 + r;
    if (gr < M) C[(size_t)gr * 16 + colc] = acc;
}

// ---------------- final: out[g] = dis_i*(sum dis_s*h3[s] + dis_i*h3[i]) + b3, i = picked[g] ----------------

__global__ void final_kernel(const float* __restrict__ h3, const float* __restrict__ dis,
                             const int* __restrict__ rowptr, const int* __restrict__ col,
                             const int* __restrict__ picked, const float* __restrict__ b3,
                             float* __restrict__ out, int G) {
    int g = blockIdx.x;
    int lane = threadIdx.x;
    if (g >= G || lane >= 16) return;
    int i = picked[g];
    float di = dis[i];
    float acc = di * h3[(size_t)i * 16 + lane];
    int e0 = rowptr[i], e1 = rowptr[i + 1];
    for (int e = e0; e < e1; e++) {
        int s = col[e];
        acc += dis[s] * h3[(size_t)s * 16 + lane];
    }
    out[(size_t)g * 16 + lane] = di * acc + b3[lane];
}

// ---------------- launch ----------------

extern "C" void kernel_launch(void* const* d_in, const int* in_sizes, int n_in,
                              void* d_out, int out_size, void* d_ws, size_t ws_size,
                              hipStream_t stream) {
    const float* x   = (const float*)d_in[0];
    const int* ei    = (const int*)d_in[1];
    const int* batch = (const int*)d_in[2];
    const float* W1  = (const float*)d_in[3];
    const float* b1  = (const float*)d_in[4];
    const float* W2  = (const float*)d_in[5];
    const float* b2  = (const float*)d_in[6];
    const float* W3  = (const float*)d_in[7];
    const float* b3  = (const float*)d_in[8];
    float* out = (float*)d_out;

    const int IN = 128, H = 256, OUT = 16;
    int N = in_sizes[0] / IN;
    int E = in_sizes[1] / 2;
    int G = out_size / OUT;
    const int* srcp = ei;
    const int* dstp = ei + E;

    char* p = (char*)d_ws;
    auto carve = [&](size_t bytes) {
        char* q = p;
        p += (bytes + 255) & ~(size_t)255;
        return q;
    };
    float* dis    = (float*)carve((size_t)N * 4);
    int*   cnt    = (int*)carve((size_t)N * 4);
    int*   rowptr = (int*)carve(((size_t)N + 1) * 4);
    int*   picked = (int*)carve((size_t)G * 4);
    int*   col    = (int*)carve((size_t)E * 4);
    float* B2     = (float*)carve((size_t)N * H * 4);  // h1, then h2
    float* B3     = (float*)carve((size_t)N * H * 4);  // aggX(128w), agg1(256w), then h3(16w)

    // CSR build
    hipMemsetAsync(cnt, 0, (size_t)N * 4, stream);
    count_kernel<<<(E + 255) / 256, 256, 0, stream>>>(dstp, cnt, E);
    dis_kernel<<<(N + 255) / 256, 256, 0, stream>>>(cnt, dis, N);
    scan_kernel<<<1, 1024, 0, stream>>>(cnt, rowptr, N);
    hipMemsetAsync(cnt, 0, (size_t)N * 4, stream);
    fill_kernel<<<(E + 255) / 256, 256, 0, stream>>>(srcp, dstp, rowptr, cnt, col, E);
    pick_kernel<<<(N + 255) / 256, 256, 0, stream>>>(batch, picked, N);

    // layer 1: aggX = A_norm x (width 128); h1 = leaky(aggX @ W1 + b1)
    agg_kernel<2><<<(N + 3) / 4, 256, 0, stream>>>(x, dis, rowptr, col, B3, N);
    gemm_f32<128, true><<<dim3((N + 127) / 128, 2), 256, 0, stream>>>(B3, W1, b1, B2, N);

    // layer 2: agg1 = A_norm h1 (width 256); h2 = leaky(agg1 @ W2 + b2)
    agg_kernel<4><<<(N + 3) / 4, 256, 0, stream>>>(B2, dis, rowptr, col, B3, N);
    gemm_f32<256, true><<<dim3((N + 127) / 128, 2), 256, 0, stream>>>(B3, W2, b2, B2, N);

    // layer 3: h3 = h2 @ W3 (width 16); out = (A_norm h3 + b3) at picked nodes
    gemm16<<<(N + 15) / 16, 256, 0, stream>>>(B2, W3, B3, N);
    final_kernel<<<G, 64, 0, stream>>>(B3, dis, rowptr, col, picked, b3, out, G);
}

// Round 2
// 468.393 us; speedup vs baseline: 1.7663x; 1.7663x over previous
//
#include <hip/hip_runtime.h>

#define NEG_SLOPE 0.01f

using short8 = __attribute__((ext_vector_type(8))) short;
using f32x4  = __attribute__((ext_vector_type(4))) float;

__device__ inline float b2f(ushort u) {
    union { unsigned u; float f; } x; x.u = ((unsigned)u) << 16; return x.f;
}
__device__ inline ushort f2b(float f) {
    union { float f; unsigned u; } x; x.f = f;
    unsigned r = x.u + 0x7FFFu + ((x.u >> 16) & 1u);  // RNE
    return (ushort)(r >> 16);
}
__device__ inline void gload16(const void* g, void* l) {
    __builtin_amdgcn_global_load_lds((__attribute__((address_space(1))) void*)g,
                                     (__attribute__((address_space(3))) void*)l, 16, 0, 0);
}

// ---------------- CSR build ----------------

__global__ void count_kernel(const int* __restrict__ dst, int* __restrict__ cnt, int E) {
    int e = blockIdx.x * blockDim.x + threadIdx.x;
    if (e < E) atomicAdd(&cnt[dst[e]], 1);
}

__global__ void dis_kernel(const int* __restrict__ cnt, float* __restrict__ dis, int N) {
    int i = blockIdx.x * blockDim.x + threadIdx.x;
    if (i < N) dis[i] = rsqrtf((float)cnt[i] + 1.0f);  // +1 = self loop
}

__global__ __launch_bounds__(1024) void scan_kernel(const int* __restrict__ cnt,
                                                    int* __restrict__ rowptr, int N) {
    __shared__ int lds[1024];
    int t = threadIdx.x;
    int CPT = (N + 1023) >> 10;
    int begin = t * CPT;
    int end = begin + CPT; if (end > N) end = N;
    int s = 0;
    for (int i = begin; i < end; i++) s += cnt[i];
    lds[t] = s;
    __syncthreads();
    for (int off = 1; off < 1024; off <<= 1) {
        int v = (t >= off) ? lds[t - off] : 0;
        __syncthreads();
        lds[t] += v;
        __syncthreads();
    }
    int run = lds[t] - s;  // exclusive prefix
    for (int i = begin; i < end; i++) { rowptr[i] = run; run += cnt[i]; }
    if (t == 1023) rowptr[N] = run;
}

__global__ void fill_kernel(const int* __restrict__ src, const int* __restrict__ dst,
                            const int* __restrict__ rowptr, int* __restrict__ fill,
                            int* __restrict__ col, int E) {
    int e = blockIdx.x * blockDim.x + threadIdx.x;
    if (e < E) {
        int d = dst[e];
        int pos = rowptr[d] + atomicAdd(&fill[d], 1);
        col[pos] = src[e];
    }
}

__global__ void pick_kernel(const int* __restrict__ batch, int* __restrict__ picked, int N) {
    int i = blockIdx.x * blockDim.x + threadIdx.x;
    if (i >= N) return;
    if (i == 0 || batch[i] != batch[i - 1]) picked[batch[i]] = i;
}

// ---------------- prep: xs = bf16(dis_i * x), Wt = bf16(W^T) ----------------

__global__ void xscale_kernel(const float* __restrict__ x, const float* __restrict__ dis,
                              ushort* __restrict__ xs, int n4) {  // n4 = N*128/4
    int idx = blockIdx.x * blockDim.x + threadIdx.x;
    if (idx >= n4) return;
    float4 v = ((const float4*)x)[idx];
    float d = dis[idx >> 5];  // 32 float4 per 128-wide row
    ushort4 o;
    o.x = f2b(v.x * d); o.y = f2b(v.y * d); o.z = f2b(v.z * d); o.w = f2b(v.w * d);
    ((ushort4*)xs)[idx] = o;
}

__global__ void wtrans_kernel(const float* __restrict__ W, ushort* __restrict__ Wt,
                              int K, int Ncol) {  // Wt[n][k] = bf16(W[k][n])
    int idx = blockIdx.x * blockDim.x + threadIdx.x;
    if (idx >= K * Ncol) return;
    int n = idx / K, k = idx - n * K;
    Wt[idx] = f2b(W[k * Ncol + n]);
}

// ---------------- aggregation: out[i] = bf16( dis_i * (sum_{s in N(i)} h[s] + h[i]) ) ----------------
// h rows are pre-scaled by dis_s, bf16. LPR = lanes per row; row width = LPR*4 bf16.

template <int LPR>
__global__ __launch_bounds__(256) void agg_kernel(const ushort* __restrict__ h,
                                                  const float* __restrict__ dis,
                                                  const int* __restrict__ rowptr,
                                                  const int* __restrict__ col,
                                                  ushort* __restrict__ out, int N) {
    constexpr int W = LPR * 4;
    constexpr int GR = 64 / LPR;
    int wave = blockIdx.x * 4 + (threadIdx.x >> 6);
    int lane = threadIdx.x & 63;
    int node = wave * GR + lane / LPR;
    int li = lane & (LPR - 1);
    if (node >= N) return;

    float di = dis[node];
    float a0, a1, a2, a3;
    {
        ushort4 v = *(const ushort4*)(h + (size_t)node * W + li * 4);  // self (already dis_i-scaled)
        a0 = b2f(v.x); a1 = b2f(v.y); a2 = b2f(v.z); a3 = b2f(v.w);
    }
    int e0 = rowptr[node], e1 = rowptr[node + 1];
    int e = e0;
    for (; e + 1 < e1; e += 2) {
        int s0 = col[e], s1 = col[e + 1];
        ushort4 v0 = *(const ushort4*)(h + (size_t)s0 * W + li * 4);
        ushort4 v1 = *(const ushort4*)(h + (size_t)s1 * W + li * 4);
        a0 += b2f(v0.x) + b2f(v1.x);
        a1 += b2f(v0.y) + b2f(v1.y);
        a2 += b2f(v0.z) + b2f(v1.z);
        a3 += b2f(v0.w) + b2f(v1.w);
    }
    if (e < e1) {
        int s0 = col[e];
        ushort4 v0 = *(const ushort4*)(h + (size_t)s0 * W + li * 4);
        a0 += b2f(v0.x); a1 += b2f(v0.y); a2 += b2f(v0.z); a3 += b2f(v0.w);
    }
    ushort4 o;
    o.x = f2b(di * a0); o.y = f2b(di * a1); o.z = f2b(di * a2); o.w = f2b(di * a3);
    *(ushort4*)(out + (size_t)node * W + li * 4) = o;
}

// ---------------- MFMA GEMM: C[M x 256] = bf16( dis_row * leaky(A[M x K] @ Bt^T + bias) ) ----------------
// A bf16 row-major [M][K]; Bt bf16 [256][K] (= W^T); C bf16 [M][256].

template <int K>
__global__ __launch_bounds__(256) void gemm_bf16(const ushort* __restrict__ A,
                                                 const ushort* __restrict__ Bt,
                                                 const float* __restrict__ bias,
                                                 const float* __restrict__ dis,
                                                 ushort* __restrict__ C, int M) {
    constexpr int BK = 64;
    __shared__ ushort As[128 * BK];
    __shared__ ushort Bs[128 * BK];
    const int t = threadIdx.x;
    const int lane = t & 63;
    const int w = t >> 6;
    const int wm = w >> 1, wn = w & 1;  // wave -> 64x64 quadrant
    const int row0 = blockIdx.x * 128;
    const int col0 = blockIdx.y * 128;

    f32x4 acc[4][4] = {};

    for (int k0 = 0; k0 < K; k0 += BK) {
        // stage 128x64 of A and Bt: 1024 16B-chunks each, 4 iters of 256 lanes
#pragma unroll
        for (int it = 0; it < 4; it++) {
            int q = it * 256 + t;          // chunk id; lane-consecutive -> lds base+lane*16
            int r = q >> 3, c = q & 7;     // row, 16B-chunk within row
            int ga = min(row0 + r, M - 1); // clamp tail (stores are guarded)
            gload16(A  + (size_t)ga * K         + k0 + c * 8, &As[q * 8]);
            gload16(Bt + (size_t)(col0 + r) * K + k0 + c * 8, &Bs[q * 8]);
        }
        __syncthreads();
#pragma unroll
        for (int ks = 0; ks < 2; ks++) {
            short8 a[4], b[4];
#pragma unroll
            for (int m = 0; m < 4; m++)
                a[m] = *(const short8*)&As[(wm * 64 + m * 16 + (lane & 15)) * BK + ks * 32 + (lane >> 4) * 8];
#pragma unroll
            for (int n = 0; n < 4; n++)
                b[n] = *(const short8*)&Bs[(wn * 64 + n * 16 + (lane & 15)) * BK + ks * 32 + (lane >> 4) * 8];
#pragma unroll
            for (int m = 0; m < 4; m++)
#pragma unroll
                for (int n = 0; n < 4; n++)
                    acc[m][n] = __builtin_amdgcn_mfma_f32_16x16x32_bf16(a[m], b[n], acc[m][n], 0, 0, 0);
        }
        __syncthreads();
    }

    // epilogue: C/D layout col=lane&15, row=(lane>>4)*4+j
#pragma unroll
    for (int m = 0; m < 4; m++) {
#pragma unroll
        for (int j = 0; j < 4; j++) {
            int grow = row0 + wm * 64 + m * 16 + (lane >> 4) * 4 + j;
            if (grow >= M) continue;
            float dr = dis[grow];
#pragma unroll
            for (int n = 0; n < 4; n++) {
                int gcol = col0 + wn * 64 + n * 16 + (lane & 15);
                float v = acc[m][n][j] + bias[gcol];
                v = v > 0.f ? v : NEG_SLOPE * v;
                C[(size_t)grow * 256 + gcol] = f2b(v * dr);
            }
        }
    }
}

// ---------------- final: per graph, aggregate h2' at the root, then 256x16 GEMM ----------------

__global__ __launch_bounds__(256) void final_kernel(const ushort* __restrict__ h2,
                                                    const float* __restrict__ dis,
                                                    const int* __restrict__ rowptr,
                                                    const int* __restrict__ col,
                                                    const int* __restrict__ picked,
                                                    const float* __restrict__ W3,
                                                    const float* __restrict__ b3,
                                                    float* __restrict__ out, int G) {
    __shared__ float agg[256];
    __shared__ float red[256];
    int g = blockIdx.x;
    int t = threadIdx.x;
    if (g >= G) return;
    int i = picked[g];
    float di = dis[i];
    float a = b2f(h2[(size_t)i * 256 + t]);  // self (dis_i-scaled already)
    for (int e = rowptr[i]; e < rowptr[i + 1]; e++) {
        int s = col[e];
        a += b2f(h2[(size_t)s * 256 + t]);
    }
    agg[t] = di * a;
    __syncthreads();
    int c = t & 15, seg = t >> 4;  // 16 cols x 16 k-segments
    float p = 0.f;
#pragma unroll
    for (int kk = 0; kk < 16; kk++) {
        int k = seg * 16 + kk;
        p += agg[k] * W3[k * 16 + c];
    }
    red[t] = p;
    __syncthreads();
    if (t < 16) {
        float sres = 0.f;
#pragma unroll
        for (int ss = 0; ss < 16; ss++) sres += red[ss * 16 + t];
        out[g * 16 + t] = sres + b3[t];
    }
}

// ---------------- launch ----------------

extern "C" void kernel_launch(void* const* d_in, const int* in_sizes, int n_in,
                              void* d_out, int out_size, void* d_ws, size_t ws_size,
                              hipStream_t stream) {
    const float* x   = (const float*)d_in[0];
    const int* ei    = (const int*)d_in[1];
    const int* batch = (const int*)d_in[2];
    const float* W1  = (const float*)d_in[3];
    const float* b1  = (const float*)d_in[4];
    const float* W2  = (const float*)d_in[5];
    const float* b2  = (const float*)d_in[6];
    const float* W3  = (const float*)d_in[7];
    const float* b3  = (const float*)d_in[8];

    const int IN = 128, H = 256, OUT = 16;
    int N = in_sizes[0] / IN;
    int E = in_sizes[1] / 2;
    int G = out_size / OUT;
    const int* srcp = ei;
    const int* dstp = ei + E;

    char* p = (char*)d_ws;
    auto carve = [&](size_t bytes) {
        char* q = p;
        p += (bytes + 255) & ~(size_t)255;
        return q;
    };
    float*  dis    = (float*)carve((size_t)N * 4);
    int*    cnt    = (int*)carve((size_t)N * 4);
    int*    rowptr = (int*)carve(((size_t)N + 1) * 4);
    int*    picked = (int*)carve((size_t)G * 4);
    int*    col    = (int*)carve((size_t)E * 4);
    ushort* W1t    = (ushort*)carve((size_t)256 * 128 * 2);
    ushort* W2t    = (ushort*)carve((size_t)256 * 256 * 2);
    ushort* R12    = (ushort*)carve((size_t)N * H * 2);  // xs | aggX, later agg1
    ushort* R3     = (ushort*)carve((size_t)N * H * 2);  // h1', later h2'

    ushort* xs   = R12;                     // [N][128]
    ushort* aggX = R12 + (size_t)N * 128;   // [N][128]
    ushort* agg1 = R12;                     // [N][256] (xs/aggX dead by then)
    ushort* h1p  = R3;                      // [N][256]
    ushort* h2p  = R3;                      // [N][256] (h1' dead by then)

    // CSR build
    hipMemsetAsync(cnt, 0, (size_t)N * 4, stream);
    count_kernel<<<(E + 255) / 256, 256, 0, stream>>>(dstp, cnt, E);
    dis_kernel<<<(N + 255) / 256, 256, 0, stream>>>(cnt, dis, N);
    scan_kernel<<<1, 1024, 0, stream>>>(cnt, rowptr, N);
    hipMemsetAsync(cnt, 0, (size_t)N * 4, stream);
    fill_kernel<<<(E + 255) / 256, 256, 0, stream>>>(srcp, dstp, rowptr, cnt, col, E);
    pick_kernel<<<(N + 255) / 256, 256, 0, stream>>>(batch, picked, N);

    // weights -> bf16 transposed; x -> dis-scaled bf16
    wtrans_kernel<<<(128 * 256 + 255) / 256, 256, 0, stream>>>(W1, W1t, 128, 256);
    wtrans_kernel<<<(256 * 256 + 255) / 256, 256, 0, stream>>>(W2, W2t, 256, 256);
    xscale_kernel<<<(N * 32 + 255) / 256, 256, 0, stream>>>(x, dis, xs, N * 32);

    // layer 1: aggX = dis*(sum xs); h1' = dis*leaky(aggX@W1 + b1)
    agg_kernel<32><<<(N + 7) / 8, 256, 0, stream>>>(xs, dis, rowptr, col, aggX, N);
    gemm_bf16<128><<<dim3((N + 127) / 128, 2), 256, 0, stream>>>(aggX, W1t, b1, dis, h1p, N);

    // layer 2: agg1 = dis*(sum h1'); h2' = dis*leaky(agg1@W2 + b2)
    agg_kernel<64><<<(N + 3) / 4, 256, 0, stream>>>(h1p, dis, rowptr, col, agg1, N);
    gemm_bf16<256><<<dim3((N + 127) / 128, 2), 256, 0, stream>>>(agg1, W2t, b2, dis, h2p, N);

    // layer 3 at picked roots only: out = (dis*(sum h2')) @ W3 + b3
    final_kernel<<<G, 256, 0, stream>>>(h2p, dis, rowptr, col, picked, W3, b3, (float*)d_out, G);
}

// Round 3
// 291.534 us; speedup vs baseline: 2.8379x; 1.6067x over previous
//
#include <hip/hip_runtime.h>

#define NEG_SLOPE 0.01f

using short8 = __attribute__((ext_vector_type(8))) short;
using f32x4  = __attribute__((ext_vector_type(4))) float;

__device__ inline float b2f(ushort u) {
    union { unsigned u; float f; } x; x.u = ((unsigned)u) << 16; return x.f;
}
__device__ inline ushort f2b(float f) {
    union { float f; unsigned u; } x; x.f = f;
    unsigned r = x.u + 0x7FFFu + ((x.u >> 16) & 1u);  // RNE
    return (ushort)(r >> 16);
}
__device__ inline void gload16(const void* g, void* l) {
    __builtin_amdgcn_global_load_lds((__attribute__((address_space(1))) void*)g,
                                     (__attribute__((address_space(3))) void*)l, 16, 0, 0);
}

// ---------------- CSR build ----------------

__global__ void count_kernel(const int* __restrict__ dst, int* __restrict__ cnt, int E) {
    int e = blockIdx.x * blockDim.x + threadIdx.x;
    if (e < E) atomicAdd(&cnt[dst[e]], 1);
}

__global__ void dis_kernel(const int* __restrict__ cnt, float* __restrict__ dis, int N) {
    int i = blockIdx.x * blockDim.x + threadIdx.x;
    if (i < N) dis[i] = rsqrtf((float)cnt[i] + 1.0f);  // +1 = self loop
}

// -------- 3-phase scan: cnt[N] -> rowptr[N+1] (exclusive). 1024 elems per block. --------

__global__ __launch_bounds__(256) void scan_phase1(const int* __restrict__ cnt,
                                                   int* __restrict__ blockSums, int N) {
    __shared__ int lds[256];
    int b = blockIdx.x, t = threadIdx.x;
    int base = b * 1024 + t * 4;
    int s = 0;
    if (base + 3 < N) {
        int4 v = *(const int4*)(cnt + base);
        s = v.x + v.y + v.z + v.w;
    } else {
        for (int i = 0; i < 4; i++) if (base + i < N) s += cnt[base + i];
    }
    lds[t] = s;
    __syncthreads();
    for (int off = 128; off > 0; off >>= 1) {
        if (t < off) lds[t] += lds[t + off];
        __syncthreads();
    }
    if (t == 0) blockSums[b] = lds[0];
}

__global__ __launch_bounds__(1024) void scan_phase2(int* __restrict__ blockSums, int nb) {
    __shared__ int lds[1024];
    int t = threadIdx.x;
    int v = (t < nb) ? blockSums[t] : 0;
    lds[t] = v;
    __syncthreads();
    for (int off = 1; off < 1024; off <<= 1) {
        int u = (t >= off) ? lds[t - off] : 0;
        __syncthreads();
        lds[t] += u;
        __syncthreads();
    }
    if (t < nb) blockSums[t] = lds[t] - v;  // exclusive
}

__global__ __launch_bounds__(256) void scan_phase3(const int* __restrict__ cnt,
                                                   const int* __restrict__ blockSums,
                                                   int* __restrict__ rowptr, int N, int E) {
    __shared__ int lds[256];
    int b = blockIdx.x, t = threadIdx.x;
    int base = b * 1024 + t * 4;
    int v[4] = {0, 0, 0, 0};
    if (base + 3 < N) {
        int4 q = *(const int4*)(cnt + base);
        v[0] = q.x; v[1] = q.y; v[2] = q.z; v[3] = q.w;
    } else {
        for (int i = 0; i < 4; i++) if (base + i < N) v[i] = cnt[base + i];
    }
    int s = v[0] + v[1] + v[2] + v[3];
    lds[t] = s;
    __syncthreads();
    for (int off = 1; off < 256; off <<= 1) {
        int u = (t >= off) ? lds[t - off] : 0;
        __syncthreads();
        lds[t] += u;
        __syncthreads();
    }
    int run = blockSums[b] + lds[t] - s;  // exclusive prefix at this thread's chunk
#pragma unroll
    for (int i = 0; i < 4; i++) {
        if (base + i < N) rowptr[base + i] = run;
        run += v[i];
    }
    if (b == 0 && t == 0) rowptr[N] = E;  // total = #edges
}

__global__ void fill_kernel(const int* __restrict__ src, const int* __restrict__ dst,
                            const int* __restrict__ rowptr, int* __restrict__ fill,
                            int* __restrict__ col, int E) {
    int e = blockIdx.x * blockDim.x + threadIdx.x;
    if (e < E) {
        int d = dst[e];
        int pos = rowptr[d] + atomicAdd(&fill[d], 1);
        col[pos] = src[e];
    }
}

__global__ void pick_kernel(const int* __restrict__ batch, int* __restrict__ picked, int N) {
    int i = blockIdx.x * blockDim.x + threadIdx.x;
    if (i >= N) return;
    if (i == 0 || batch[i] != batch[i - 1]) picked[batch[i]] = i;
}

// ---------------- prep: xs = bf16(dis_i * x), Wt = bf16(W^T) ----------------

__global__ void xscale_kernel(const float* __restrict__ x, const float* __restrict__ dis,
                              ushort* __restrict__ xs, int n4) {  // n4 = N*128/4
    int idx = blockIdx.x * blockDim.x + threadIdx.x;
    if (idx >= n4) return;
    float4 v = ((const float4*)x)[idx];
    float d = dis[idx >> 5];  // 32 float4 per 128-wide row
    ushort4 o;
    o.x = f2b(v.x * d); o.y = f2b(v.y * d); o.z = f2b(v.z * d); o.w = f2b(v.w * d);
    ((ushort4*)xs)[idx] = o;
}

__global__ void wtrans_kernel(const float* __restrict__ W, ushort* __restrict__ Wt,
                              int K, int Ncol) {  // Wt[n][k] = bf16(W[k][n])
    int idx = blockIdx.x * blockDim.x + threadIdx.x;
    if (idx >= K * Ncol) return;
    int n = idx / K, k = idx - n * K;
    Wt[idx] = f2b(W[k * Ncol + n]);
}

// ---------------- aggregation: out[i] = bf16( dis_i * (sum_{s in N(i)} h[s] + h[i]) ) ----------------
// h rows pre-scaled by dis_s, bf16. LPR lanes per row, 8 bf16 (16 B) per lane; width = LPR*8.

template <int LPR>
__global__ __launch_bounds__(256) void agg_kernel(const ushort* __restrict__ h,
                                                  const float* __restrict__ dis,
                                                  const int* __restrict__ rowptr,
                                                  const int* __restrict__ col,
                                                  ushort* __restrict__ out, int N) {
    constexpr int W = LPR * 8;
    constexpr int GR = 64 / LPR;
    int wave = blockIdx.x * 4 + (threadIdx.x >> 6);
    int lane = threadIdx.x & 63;
    int node = wave * GR + lane / LPR;
    int li = lane & (LPR - 1);
    if (node >= N) return;

    float di = dis[node];
    float a[8];
    {
        short8 v = *(const short8*)(h + (size_t)node * W + li * 8);  // self (dis_i-scaled)
#pragma unroll
        for (int j = 0; j < 8; j++) a[j] = b2f((ushort)v[j]);
    }
    int e0 = rowptr[node], e1 = rowptr[node + 1];
    int e = e0;
    for (; e + 1 < e1; e += 2) {
        int s0 = col[e], s1 = col[e + 1];
        short8 v0 = *(const short8*)(h + (size_t)s0 * W + li * 8);
        short8 v1 = *(const short8*)(h + (size_t)s1 * W + li * 8);
#pragma unroll
        for (int j = 0; j < 8; j++) a[j] += b2f((ushort)v0[j]) + b2f((ushort)v1[j]);
    }
    if (e < e1) {
        int s0 = col[e];
        short8 v0 = *(const short8*)(h + (size_t)s0 * W + li * 8);
#pragma unroll
        for (int j = 0; j < 8; j++) a[j] += b2f((ushort)v0[j]);
    }
    short8 o;
#pragma unroll
    for (int j = 0; j < 8; j++) o[j] = (short)f2b(di * a[j]);
    *(short8*)(out + (size_t)node * W + li * 8) = o;
}

// ---------------- MFMA GEMM: C[M x 256] = bf16( dis_row * leaky(A[M x K] @ Bt^T + bias) ) ----------------
// A bf16 row-major [M][K]; Bt bf16 [256][K] (= W^T); C bf16 [M][256].

template <int K>
__global__ __launch_bounds__(256) void gemm_bf16(const ushort* __restrict__ A,
                                                 const ushort* __restrict__ Bt,
                                                 const float* __restrict__ bias,
                                                 const float* __restrict__ dis,
                                                 ushort* __restrict__ C, int M) {
    constexpr int BK = 64;
    __shared__ ushort As[128 * BK];
    __shared__ ushort Bs[128 * BK];
    const int t = threadIdx.x;
    const int lane = t & 63;
    const int w = t >> 6;
    const int wm = w >> 1, wn = w & 1;  // wave -> 64x64 quadrant
    const int row0 = blockIdx.x * 128;
    const int col0 = blockIdx.y * 128;

    f32x4 acc[4][4] = {};

    for (int k0 = 0; k0 < K; k0 += BK) {
#pragma unroll
        for (int it = 0; it < 4; it++) {
            int q = it * 256 + t;          // chunk id; lane-consecutive -> lds base+lane*16
            int r = q >> 3, c = q & 7;     // row, 16B-chunk within row
            int ga = min(row0 + r, M - 1); // clamp tail (stores are guarded)
            gload16(A  + (size_t)ga * K         + k0 + c * 8, &As[q * 8]);
            gload16(Bt + (size_t)(col0 + r) * K + k0 + c * 8, &Bs[q * 8]);
        }
        __syncthreads();
#pragma unroll
        for (int ks = 0; ks < 2; ks++) {
            short8 a[4], b[4];
#pragma unroll
            for (int m = 0; m < 4; m++)
                a[m] = *(const short8*)&As[(wm * 64 + m * 16 + (lane & 15)) * BK + ks * 32 + (lane >> 4) * 8];
#pragma unroll
            for (int n = 0; n < 4; n++)
                b[n] = *(const short8*)&Bs[(wn * 64 + n * 16 + (lane & 15)) * BK + ks * 32 + (lane >> 4) * 8];
#pragma unroll
            for (int m = 0; m < 4; m++)
#pragma unroll
                for (int n = 0; n < 4; n++)
                    acc[m][n] = __builtin_amdgcn_mfma_f32_16x16x32_bf16(a[m], b[n], acc[m][n], 0, 0, 0);
        }
        __syncthreads();
    }

    // epilogue: C/D layout col=lane&15, row=(lane>>4)*4+j
#pragma unroll
    for (int m = 0; m < 4; m++) {
#pragma unroll
        for (int j = 0; j < 4; j++) {
            int grow = row0 + wm * 64 + m * 16 + (lane >> 4) * 4 + j;
            if (grow >= M) continue;
            float dr = dis[grow];
#pragma unroll
            for (int n = 0; n < 4; n++) {
                int gcol = col0 + wn * 64 + n * 16 + (lane & 15);
                float v = acc[m][n][j] + bias[gcol];
                v = v > 0.f ? v : NEG_SLOPE * v;
                C[(size_t)grow * 256 + gcol] = f2b(v * dr);
            }
        }
    }
}

// ---------------- final: per graph, aggregate h2' at the root, then 256x16 GEMM ----------------

__global__ __launch_bounds__(256) void final_kernel(const ushort* __restrict__ h2,
                                                    const float* __restrict__ dis,
                                                    const int* __restrict__ rowptr,
                                                    const int* __restrict__ col,
                                                    const int* __restrict__ picked,
                                                    const float* __restrict__ W3,
                                                    const float* __restrict__ b3,
                                                    float* __restrict__ out, int G) {
    __shared__ float agg[256];
    __shared__ float red[256];
    int g = blockIdx.x;
    int t = threadIdx.x;
    if (g >= G) return;
    int i = picked[g];
    float di = dis[i];
    float a = b2f(h2[(size_t)i * 256 + t]);  // self (dis_i-scaled already)
    for (int e = rowptr[i]; e < rowptr[i + 1]; e++) {
        int s = col[e];
        a += b2f(h2[(size_t)s * 256 + t]);
    }
    agg[t] = di * a;
    __syncthreads();
    int c = t & 15, seg = t >> 4;  // 16 cols x 16 k-segments
    float p = 0.f;
#pragma unroll
    for (int kk = 0; kk < 16; kk++) {
        int k = seg * 16 + kk;
        p += agg[k] * W3[k * 16 + c];
    }
    red[t] = p;
    __syncthreads();
    if (t < 16) {
        float sres = 0.f;
#pragma unroll
        for (int ss = 0; ss < 16; ss++) sres += red[ss * 16 + t];
        out[g * 16 + t] = sres + b3[t];
    }
}

// ---------------- launch ----------------

extern "C" void kernel_launch(void* const* d_in, const int* in_sizes, int n_in,
                              void* d_out, int out_size, void* d_ws, size_t ws_size,
                              hipStream_t stream) {
    const float* x   = (const float*)d_in[0];
    const int* ei    = (const int*)d_in[1];
    const int* batch = (const int*)d_in[2];
    const float* W1  = (const float*)d_in[3];
    const float* b1  = (const float*)d_in[4];
    const float* W2  = (const float*)d_in[5];
    const float* b2  = (const float*)d_in[6];
    const float* W3  = (const float*)d_in[7];
    const float* b3  = (const float*)d_in[8];

    const int IN = 128, H = 256, OUT = 16;
    int N = in_sizes[0] / IN;
    int E = in_sizes[1] / 2;
    int G = out_size / OUT;
    const int* srcp = ei;
    const int* dstp = ei + E;

    char* p = (char*)d_ws;
    auto carve = [&](size_t bytes) {
        char* q = p;
        p += (bytes + 255) & ~(size_t)255;
        return q;
    };
    float*  dis    = (float*)carve((size_t)N * 4);
    int*    cnt    = (int*)carve((size_t)N * 4);
    int*    rowptr = (int*)carve(((size_t)N + 1) * 4);
    int*    bsums  = (int*)carve(1024 * 4);
    int*    picked = (int*)carve((size_t)G * 4);
    int*    col    = (int*)carve((size_t)E * 4);
    ushort* W1t    = (ushort*)carve((size_t)256 * 128 * 2);
    ushort* W2t    = (ushort*)carve((size_t)256 * 256 * 2);
    ushort* R12    = (ushort*)carve((size_t)N * H * 2);  // xs | aggX, later agg1
    ushort* R3     = (ushort*)carve((size_t)N * H * 2);  // h1', later h2'

    ushort* xs   = R12;                     // [N][128]
    ushort* aggX = R12 + (size_t)N * 128;   // [N][128]
    ushort* agg1 = R12;                     // [N][256] (xs/aggX dead by then)
    ushort* h1p  = R3;                      // [N][256]
    ushort* h2p  = R3;                      // [N][256] (h1' dead by then)

    int nb = (N + 1023) / 1024;  // scan blocks (<= 1024)

    // CSR build
    hipMemsetAsync(cnt, 0, (size_t)N * 4, stream);
    count_kernel<<<(E + 255) / 256, 256, 0, stream>>>(dstp, cnt, E);
    dis_kernel<<<(N + 255) / 256, 256, 0, stream>>>(cnt, dis, N);
    scan_phase1<<<nb, 256, 0, stream>>>(cnt, bsums, N);
    scan_phase2<<<1, 1024, 0, stream>>>(bsums, nb);
    scan_phase3<<<nb, 256, 0, stream>>>(cnt, bsums, rowptr, N, E);
    hipMemsetAsync(cnt, 0, (size_t)N * 4, stream);
    fill_kernel<<<(E + 255) / 256, 256, 0, stream>>>(srcp, dstp, rowptr, cnt, col, E);
    pick_kernel<<<(N + 255) / 256, 256, 0, stream>>>(batch, picked, N);

    // weights -> bf16 transposed; x -> dis-scaled bf16
    wtrans_kernel<<<(128 * 256 + 255) / 256, 256, 0, stream>>>(W1, W1t, 128, 256);
    wtrans_kernel<<<(256 * 256 + 255) / 256, 256, 0, stream>>>(W2, W2t, 256, 256);
    xscale_kernel<<<(N * 32 + 255) / 256, 256, 0, stream>>>(x, dis, xs, N * 32);

    // layer 1: aggX = dis*(sum xs); h1' = dis*leaky(aggX@W1 + b1)
    agg_kernel<16><<<(N + 15) / 16, 256, 0, stream>>>(xs, dis, rowptr, col, aggX, N);
    gemm_bf16<128><<<dim3((N + 127) / 128, 2), 256, 0, stream>>>(aggX, W1t, b1, dis, h1p, N);

    // layer 2: agg1 = dis*(sum h1'); h2' = dis*leaky(agg1@W2 + b2)
    agg_kernel<32><<<(N + 7) / 8, 256, 0, stream>>>(h1p, dis, rowptr, col, agg1, N);
    gemm_bf16<256><<<dim3((N + 127) / 128, 2), 256, 0, stream>>>(agg1, W2t, b2, dis, h2p, N);

    // layer 3 at picked roots only: out = (dis*(sum h2')) @ W3 + b3
    final_kernel<<<G, 256, 0, stream>>>(h2p, dis, rowptr, col, picked, W3, b3, (float*)d_out, G);
}

// Round 4
// 285.375 us; speedup vs baseline: 2.8991x; 1.0216x over previous
//
#include <hip/hip_runtime.h>

#define NEG_SLOPE 0.01f

using short8 = __attribute__((ext_vector_type(8))) short;
using f32x4  = __attribute__((ext_vector_type(4))) float;

__device__ inline float b2f(ushort u) {
    union { unsigned u; float f; } x; x.u = ((unsigned)u) << 16; return x.f;
}
__device__ inline ushort f2b(float f) {
    union { float f; unsigned u; } x; x.f = f;
    unsigned r = x.u + 0x7FFFu + ((x.u >> 16) & 1u);  // RNE
    return (ushort)(r >> 16);
}
__device__ inline void gload16(const void* g, void* l) {
    __builtin_amdgcn_global_load_lds((__attribute__((address_space(1))) void*)g,
                                     (__attribute__((address_space(3))) void*)l, 16, 0, 0);
}

// ---------------- CSR build ----------------

// fused: per-edge degree count + per-node graph-root pick
__global__ void count_pick(const int* __restrict__ dst, int* __restrict__ cnt, int E,
                           const int* __restrict__ batch, int* __restrict__ picked, int N) {
    int i = blockIdx.x * blockDim.x + threadIdx.x;
    if (i < E) atomicAdd(&cnt[dst[i]], 1);
    if (i < N) {
        if (i == 0 || batch[i] != batch[i - 1]) picked[batch[i]] = i;
    }
}

// phase 1: per-block (1024 elems) reduce + fused dis = rsqrt(deg+1)
__global__ __launch_bounds__(256) void scan_phase1(const int* __restrict__ cnt,
                                                   int* __restrict__ blockSums,
                                                   float* __restrict__ dis, int N) {
    __shared__ int lds[256];
    int b = blockIdx.x, t = threadIdx.x;
    int base = b * 1024 + t * 4;
    int v[4] = {0, 0, 0, 0};
    if (base + 3 < N) {
        int4 q = *(const int4*)(cnt + base);
        v[0] = q.x; v[1] = q.y; v[2] = q.z; v[3] = q.w;
    } else {
        for (int i = 0; i < 4; i++) if (base + i < N) v[i] = cnt[base + i];
    }
#pragma unroll
    for (int i = 0; i < 4; i++)
        if (base + i < N) dis[base + i] = rsqrtf((float)v[i] + 1.0f);
    lds[t] = v[0] + v[1] + v[2] + v[3];
    __syncthreads();
    for (int off = 128; off > 0; off >>= 1) {
        if (t < off) lds[t] += lds[t + off];
        __syncthreads();
    }
    if (t == 0) blockSums[b] = lds[0];
}

__global__ __launch_bounds__(1024) void scan_phase2(int* __restrict__ blockSums, int nb) {
    __shared__ int lds[1024];
    int t = threadIdx.x;
    int v = (t < nb) ? blockSums[t] : 0;
    lds[t] = v;
    __syncthreads();
    for (int off = 1; off < 1024; off <<= 1) {
        int u = (t >= off) ? lds[t - off] : 0;
        __syncthreads();
        lds[t] += u;
        __syncthreads();
    }
    if (t < nb) blockSums[t] = lds[t] - v;  // exclusive
}

// phase 3: write rowptr AND a cursor copy (so fill needs no extra memset)
__global__ __launch_bounds__(256) void scan_phase3(const int* __restrict__ cnt,
                                                   const int* __restrict__ blockSums,
                                                   int* __restrict__ rowptr,
                                                   int* __restrict__ cur, int N, int E) {
    __shared__ int lds[256];
    int b = blockIdx.x, t = threadIdx.x;
    int base = b * 1024 + t * 4;
    int v[4] = {0, 0, 0, 0};
    if (base + 3 < N) {
        int4 q = *(const int4*)(cnt + base);
        v[0] = q.x; v[1] = q.y; v[2] = q.z; v[3] = q.w;
    } else {
        for (int i = 0; i < 4; i++) if (base + i < N) v[i] = cnt[base + i];
    }
    int s = v[0] + v[1] + v[2] + v[3];
    lds[t] = s;
    __syncthreads();
    for (int off = 1; off < 256; off <<= 1) {
        int u = (t >= off) ? lds[t - off] : 0;
        __syncthreads();
        lds[t] += u;
        __syncthreads();
    }
    int run = blockSums[b] + lds[t] - s;
#pragma unroll
    for (int i = 0; i < 4; i++) {
        if (base + i < N) { rowptr[base + i] = run; cur[base + i] = run; }
        run += v[i];
    }
    if (b == 0 && t == 0) rowptr[N] = E;
}

__global__ void fill_kernel(const int* __restrict__ src, const int* __restrict__ dst,
                            int* __restrict__ cur, int* __restrict__ col, int E) {
    int e = blockIdx.x * blockDim.x + threadIdx.x;
    if (e < E) {
        int pos = atomicAdd(&cur[dst[e]], 1);
        col[pos] = src[e];
    }
}

// ---------------- fused prep: W1t, W2t (bf16 transposed), xs = bf16(dis*x) ----------------

__global__ void prep_kernel(const float* __restrict__ W1, ushort* __restrict__ W1t,
                            const float* __restrict__ W2, ushort* __restrict__ W2t,
                            const float* __restrict__ x, const float* __restrict__ dis,
                            ushort* __restrict__ xs, int n4) {  // n4 = N*128/4
    int idx = blockIdx.x * blockDim.x + threadIdx.x;
    if (idx < 32768) {                       // W1t[n][k] = W1[k][n], K=128
        int n = idx >> 7, k = idx & 127;
        W1t[idx] = f2b(W1[k * 256 + n]);
    } else if (idx < 98304) {                // W2t[n][k] = W2[k][n], K=256
        int j = idx - 32768;
        int n = j >> 8, k = j & 255;
        W2t[j] = f2b(W2[k * 256 + n]);
    } else {
        int j = idx - 98304;
        if (j < n4) {
            float4 v = ((const float4*)x)[j];
            float d = dis[j >> 5];           // 32 float4 per 128-wide row
            ushort4 o;
            o.x = f2b(v.x * d); o.y = f2b(v.y * d); o.z = f2b(v.z * d); o.w = f2b(v.w * d);
            ((ushort4*)xs)[j] = o;
        }
    }
}

// ---------------- aggregation: out[i] = bf16( dis_i * (sum_{s in N(i)} h[s] + h[i]) ) ----------------
// h rows pre-scaled by dis_s, bf16. LPR lanes per row, 8 bf16 (16 B) per lane; width = LPR*8.
// 4-edge unroll for memory-level parallelism.

template <int LPR>
__global__ __launch_bounds__(256) void agg_kernel(const ushort* __restrict__ h,
                                                  const float* __restrict__ dis,
                                                  const int* __restrict__ rowptr,
                                                  const int* __restrict__ col,
                                                  ushort* __restrict__ out, int N) {
    constexpr int W = LPR * 8;
    constexpr int GR = 64 / LPR;
    int wave = blockIdx.x * 4 + (threadIdx.x >> 6);
    int lane = threadIdx.x & 63;
    int node = wave * GR + lane / LPR;
    int li = lane & (LPR - 1);
    if (node >= N) return;

    const ushort* hp = h + (size_t)li * 8;
    float di = dis[node];
    float a[8];
    {
        short8 v = *(const short8*)(hp + (size_t)node * W);  // self (dis_i-scaled)
#pragma unroll
        for (int j = 0; j < 8; j++) a[j] = b2f((ushort)v[j]);
    }
    int e = rowptr[node], e1 = rowptr[node + 1];
    for (; e + 4 <= e1; e += 4) {
        int s0 = col[e], s1 = col[e + 1], s2 = col[e + 2], s3 = col[e + 3];
        short8 v0 = *(const short8*)(hp + (size_t)s0 * W);
        short8 v1 = *(const short8*)(hp + (size_t)s1 * W);
        short8 v2 = *(const short8*)(hp + (size_t)s2 * W);
        short8 v3 = *(const short8*)(hp + (size_t)s3 * W);
#pragma unroll
        for (int j = 0; j < 8; j++)
            a[j] += (b2f((ushort)v0[j]) + b2f((ushort)v1[j])) +
                    (b2f((ushort)v2[j]) + b2f((ushort)v3[j]));
    }
    for (; e < e1; e++) {
        int s0 = col[e];
        short8 v0 = *(const short8*)(hp + (size_t)s0 * W);
#pragma unroll
        for (int j = 0; j < 8; j++) a[j] += b2f((ushort)v0[j]);
    }
    short8 o;
#pragma unroll
    for (int j = 0; j < 8; j++) o[j] = (short)f2b(di * a[j]);
    *(short8*)(out + (size_t)node * W + li * 8) = o;
}

// ---------------- MFMA GEMM: C[M x 256] = bf16( dis_row * leaky(A[M x K] @ Bt^T + bias) ) ----------------
// A bf16 row-major [M][K]; Bt bf16 [256][K] (= W^T); C bf16 [M][256].
// LDS tiles XOR-swizzled (T2): chunk c of row r stored at chunk c^(r&7); source pre-swizzled
// so global_load_lds' linear dest yields the swizzled layout (both-sides-or-neither).

template <int K>
__global__ __launch_bounds__(256) void gemm_bf16(const ushort* __restrict__ A,
                                                 const ushort* __restrict__ Bt,
                                                 const float* __restrict__ bias,
                                                 const float* __restrict__ dis,
                                                 ushort* __restrict__ C, int M) {
    constexpr int BK = 64;
    __shared__ ushort As[128 * BK];
    __shared__ ushort Bs[128 * BK];
    const int t = threadIdx.x;
    const int lane = t & 63;
    const int w = t >> 6;
    const int wm = w >> 1, wn = w & 1;  // wave -> 64x64 quadrant
    const int row0 = blockIdx.x * 128;
    const int col0 = blockIdx.y * 128;

    f32x4 acc[4][4] = {};

    for (int k0 = 0; k0 < K; k0 += BK) {
#pragma unroll
        for (int it = 0; it < 4; it++) {
            int q = it * 256 + t;            // chunk id; lane-consecutive -> lds base+lane*16
            int r = q >> 3, c = q & 7;       // row, 16B-chunk within row
            int cs = c ^ (r & 7);            // pre-swizzled source chunk
            int ga = min(row0 + r, M - 1);   // clamp tail (stores are guarded)
            gload16(A  + (size_t)ga * K         + k0 + cs * 8, &As[q * 8]);
            gload16(Bt + (size_t)(col0 + r) * K + k0 + cs * 8, &Bs[q * 8]);
        }
        __syncthreads();
#pragma unroll
        for (int ks = 0; ks < 2; ks++) {
            short8 a[4], b[4];
            int cc = ks * 4 + (lane >> 4);   // 16B-chunk within row for this fragment
#pragma unroll
            for (int m = 0; m < 4; m++) {
                int R = wm * 64 + m * 16 + (lane & 15);
                a[m] = *(const short8*)&As[R * BK + ((cc ^ (R & 7)) * 8)];
            }
#pragma unroll
            for (int n = 0; n < 4; n++) {
                int R = wn * 64 + n * 16 + (lane & 15);
                b[n] = *(const short8*)&Bs[R * BK + ((cc ^ (R & 7)) * 8)];
            }
#pragma unroll
            for (int m = 0; m < 4; m++)
#pragma unroll
                for (int n = 0; n < 4; n++)
                    acc[m][n] = __builtin_amdgcn_mfma_f32_16x16x32_bf16(a[m], b[n], acc[m][n], 0, 0, 0);
        }
        __syncthreads();
    }

    // epilogue: C/D layout col=lane&15, row=(lane>>4)*4+j
#pragma unroll
    for (int m = 0; m < 4; m++) {
#pragma unroll
        for (int j = 0; j < 4; j++) {
            int grow = row0 + wm * 64 + m * 16 + (lane >> 4) * 4 + j;
            if (grow >= M) continue;
            float dr = dis[grow];
#pragma unroll
            for (int n = 0; n < 4; n++) {
                int gcol = col0 + wn * 64 + n * 16 + (lane & 15);
                float v = acc[m][n][j] + bias[gcol];
                v = v > 0.f ? v : NEG_SLOPE * v;
                C[(size_t)grow * 256 + gcol] = f2b(v * dr);
            }
        }
    }
}

// ---------------- final: per graph, aggregate h2' at the root, then 256x16 GEMM ----------------

__global__ __launch_bounds__(256) void final_kernel(const ushort* __restrict__ h2,
                                                    const float* __restrict__ dis,
                                                    const int* __restrict__ rowptr,
                                                    const int* __restrict__ col,
                                                    const int* __restrict__ picked,
                                                    const float* __restrict__ W3,
                                                    const float* __restrict__ b3,
                                                    float* __restrict__ out, int G) {
    __shared__ float agg[256];
    __shared__ float red[256];
    int g = blockIdx.x;
    int t = threadIdx.x;
    if (g >= G) return;
    int i = picked[g];
    float di = dis[i];
    float a = b2f(h2[(size_t)i * 256 + t]);  // self (dis_i-scaled already)
    for (int e = rowptr[i]; e < rowptr[i + 1]; e++) {
        int s = col[e];
        a += b2f(h2[(size_t)s * 256 + t]);
    }
    agg[t] = di * a;
    __syncthreads();
    int c = t & 15, seg = t >> 4;  // 16 cols x 16 k-segments
    float p = 0.f;
#pragma unroll
    for (int kk = 0; kk < 16; kk++) {
        int k = seg * 16 + kk;
        p += agg[k] * W3[k * 16 + c];
    }
    red[t] = p;
    __syncthreads();
    if (t < 16) {
        float sres = 0.f;
#pragma unroll
        for (int ss = 0; ss < 16; ss++) sres += red[ss * 16 + t];
        out[g * 16 + t] = sres + b3[t];
    }
}

// ---------------- launch ----------------

extern "C" void kernel_launch(void* const* d_in, const int* in_sizes, int n_in,
                              void* d_out, int out_size, void* d_ws, size_t ws_size,
                              hipStream_t stream) {
    const float* x   = (const float*)d_in[0];
    const int* ei    = (const int*)d_in[1];
    const int* batch = (const int*)d_in[2];
    const float* W1  = (const float*)d_in[3];
    const float* b1  = (const float*)d_in[4];
    const float* W2  = (const float*)d_in[5];
    const float* b2  = (const float*)d_in[6];
    const float* W3  = (const float*)d_in[7];
    const float* b3  = (const float*)d_in[8];

    const int IN = 128, H = 256, OUT = 16;
    int N = in_sizes[0] / IN;
    int E = in_sizes[1] / 2;
    int G = out_size / OUT;
    const int* srcp = ei;
    const int* dstp = ei + E;

    char* p = (char*)d_ws;
    auto carve = [&](size_t bytes) {
        char* q = p;
        p += (bytes + 255) & ~(size_t)255;
        return q;
    };
    float*  dis    = (float*)carve((size_t)N * 4);
    int*    cnt    = (int*)carve((size_t)N * 4);
    int*    rowptr = (int*)carve(((size_t)N + 1) * 4);
    int*    cur    = (int*)carve((size_t)N * 4);
    int*    bsums  = (int*)carve(1024 * 4);
    int*    picked = (int*)carve((size_t)G * 4);
    int*    col    = (int*)carve((size_t)E * 4);
    ushort* W1t    = (ushort*)carve((size_t)256 * 128 * 2);
    ushort* W2t    = (ushort*)carve((size_t)256 * 256 * 2);
    ushort* R12    = (ushort*)carve((size_t)N * H * 2);  // xs | aggX, later agg1
    ushort* R3     = (ushort*)carve((size_t)N * H * 2);  // h1', later h2'

    ushort* xs   = R12;                     // [N][128]
    ushort* aggX = R12 + (size_t)N * 128;   // [N][128]
    ushort* agg1 = R12;                     // [N][256] (xs/aggX dead by then)
    ushort* h1p  = R3;                      // [N][256]
    ushort* h2p  = R3;                      // [N][256] (h1' dead by then)

    int nb = (N + 1023) / 1024;
    int cpN = (E > N ? E : N);

    // CSR build (7 dispatches incl. memset)
    hipMemsetAsync(cnt, 0, (size_t)N * 4, stream);
    count_pick<<<(cpN + 255) / 256, 256, 0, stream>>>(dstp, cnt, E, batch, picked, N);
    scan_phase1<<<nb, 256, 0, stream>>>(cnt, bsums, dis, N);
    scan_phase2<<<1, 1024, 0, stream>>>(bsums, nb);
    scan_phase3<<<nb, 256, 0, stream>>>(cnt, bsums, rowptr, cur, N, E);
    fill_kernel<<<(E + 255) / 256, 256, 0, stream>>>(srcp, dstp, cur, col, E);

    // fused weights-transpose + x-scale
    prep_kernel<<<(98304 + N * 32 + 255) / 256, 256, 0, stream>>>(W1, W1t, W2, W2t, x, dis, xs, N * 32);

    // layer 1: aggX = dis*(sum xs); h1' = dis*leaky(aggX@W1 + b1)
    agg_kernel<16><<<(N + 15) / 16, 256, 0, stream>>>(xs, dis, rowptr, col, aggX, N);
    gemm_bf16<128><<<dim3((N + 127) / 128, 2), 256, 0, stream>>>(aggX, W1t, b1, dis, h1p, N);

    // layer 2: agg1 = dis*(sum h1'); h2' = dis*leaky(agg1@W2 + b2)
    agg_kernel<32><<<(N + 7) / 8, 256, 0, stream>>>(h1p, dis, rowptr, col, agg1, N);
    gemm_bf16<256><<<dim3((N + 127) / 128, 2), 256, 0, stream>>>(agg1, W2t, b2, dis, h2p, N);

    // layer 3 at picked roots only: out = (dis*(sum h2')) @ W3 + b3
    final_kernel<<<G, 256, 0, stream>>>(h2p, dis, rowptr, col, picked, W3, b3, (float*)d_out, G);
}